// Round 2
// baseline (130.027 us; speedup 1.0000x reference)
//
#include <hip/hip_runtime.h>
#include <stdint.h>
#include <math.h>

#define BB 4
#define LL 12
#define NN 512
#define DMM 64
#define HH 8
#define DD 8
#define SK 35
#define IDX_TOTAL (NN*SK)   // 17920
#define PADK 12             // 48B row pitch: b128-aligned, conflict-free bank walk

// ---------------------------------------------------------------------------
// Threefry-2x32 (JAX-exact: 20 rounds, rotations {13,15,26,6}/{17,29,16,24})
// ---------------------------------------------------------------------------
__device__ __forceinline__ void tf2x32(uint32_t k0, uint32_t k1, uint32_t x0, uint32_t x1,
                                       uint32_t& o0, uint32_t& o1) {
  const uint32_t ks2 = k0 ^ k1 ^ 0x1BD11BDAu;
  uint32_t a = x0 + k0, b = x1 + k1;
#define TF_R(r) { a += b; b = (b << (r)) | (b >> (32 - (r))); b ^= a; }
  TF_R(13) TF_R(15) TF_R(26) TF_R(6)
  a += k1;  b += ks2 + 1u;
  TF_R(17) TF_R(29) TF_R(16) TF_R(24)
  a += ks2; b += k0 + 2u;
  TF_R(13) TF_R(15) TF_R(26) TF_R(6)
  a += k0;  b += k1 + 3u;
  TF_R(17) TF_R(29) TF_R(16) TF_R(24)
  a += k1;  b += ks2 + 4u;
  TF_R(13) TF_R(15) TF_R(26) TF_R(6)
  a += ks2; b += k0 + 5u;
#undef TF_R
  o0 = a; o1 = b;
}

// ---------------------------------------------------------------------------
// K1: fused projections (y=0,1,2) + idx generation (y=3).
// Proj: X:(B,L,N,64) @ W:(64,64) + b -> O layout [b][h][l][n][d]
// idxT layout: [s][r] (s=0..34, r=0..511) for coalesced per-s reads.
// ---------------------------------------------------------------------------
__global__ __launch_bounds__(256) void proj_idx_kernel(
    const float* __restrict__ Xq, const float* __restrict__ Xk, const float* __restrict__ Xv,
    const float* __restrict__ Wq_, const float* __restrict__ Wk_, const float* __restrict__ Wv_,
    const float* __restrict__ bq_, const float* __restrict__ bk_, const float* __restrict__ bv_,
    float* __restrict__ Oq, float* __restrict__ Ok, float* __restrict__ Ov,
    int* __restrict__ idxT) {
  const int tz = blockIdx.y;
  if (tz == 3) {
    int gid = blockIdx.x * 256 + threadIdx.x;
    if (gid < IDX_TOTAL) {
      int r = gid & (NN - 1);     // idxT flat = s*512 + r
      int s = gid >> 9;
      uint32_t ka, kb;
      tf2x32(0u, 42u, 0u, 1u, ka, kb);
      uint32_t b1, b2;
      tf2x32(ka, kb, 0u, (uint32_t)(r * SK + s), b1, b2);   // counter = row-major (r,s)
      idxT[gid] = (int)((b1 ^ b2) & (uint32_t)(NN - 1));
    }
    return;
  }
  const float* X    = (tz == 0) ? Xq  : (tz == 1) ? Xk  : Xv;
  const float* W    = (tz == 0) ? Wq_ : (tz == 1) ? Wk_ : Wv_;
  const float* bias = (tz == 0) ? bq_ : (tz == 1) ? bk_ : bv_;
  float* O          = (tz == 0) ? Oq  : (tz == 1) ? Ok  : Ov;

  __shared__ __align__(16) float Ws[64][64];
  __shared__ __align__(16) float Xs[128][68];
  __shared__ float bs[64];

  const int tid = threadIdx.x;
  for (int i = tid; i < 1024; i += 256)
    ((float4*)Ws)[i] = ((const float4*)W)[i];
  if (tid < 64) bs[tid] = bias[tid];
  const size_t rowBase = (size_t)blockIdx.x * 128;
  const float* Xb = X + rowBase * 64;
  for (int i = tid; i < 2048; i += 256) {
    int r = i >> 4, c = (i & 15) << 2;
    *(float4*)&Xs[r][c] = ((const float4*)Xb)[i];
  }
  __syncthreads();

  const int hcol = tid & 7;
  const int rb   = tid >> 3;
  float4 bv0 = *(float4*)&bs[hcol*8];
  float4 bv1 = *(float4*)&bs[hcol*8+4];
  float acc[4][8];
  #pragma unroll
  for (int i = 0; i < 4; ++i) {
    acc[i][0]=bv0.x; acc[i][1]=bv0.y; acc[i][2]=bv0.z; acc[i][3]=bv0.w;
    acc[i][4]=bv1.x; acc[i][5]=bv1.y; acc[i][6]=bv1.z; acc[i][7]=bv1.w;
  }
  #pragma unroll 4
  for (int m = 0; m < 64; ++m) {
    float4 w0 = *(const float4*)&Ws[m][hcol*8];
    float4 w1 = *(const float4*)&Ws[m][hcol*8+4];
    #pragma unroll
    for (int i = 0; i < 4; ++i) {
      float x = Xs[rb + 32*i][m];
      acc[i][0] = fmaf(x, w0.x, acc[i][0]);
      acc[i][1] = fmaf(x, w0.y, acc[i][1]);
      acc[i][2] = fmaf(x, w0.z, acc[i][2]);
      acc[i][3] = fmaf(x, w0.w, acc[i][3]);
      acc[i][4] = fmaf(x, w1.x, acc[i][4]);
      acc[i][5] = fmaf(x, w1.y, acc[i][5]);
      acc[i][6] = fmaf(x, w1.z, acc[i][6]);
      acc[i][7] = fmaf(x, w1.w, acc[i][7]);
    }
  }
  #pragma unroll
  for (int i = 0; i < 4; ++i) {
    size_t R = rowBase + rb + 32*i;
    int bI = (int)(R / (LL*NN));
    int lI = (int)((R / NN) % LL);
    int nI = (int)(R % NN);
    size_t off = ((((size_t)bI*HH + hcol)*LL + lI)*NN + nI)*DD;
    *(float4*)&O[off]     = make_float4(acc[i][0],acc[i][1],acc[i][2],acc[i][3]);
    *(float4*)&O[off + 4] = make_float4(acc[i][4],acc[i][5],acc[i][6],acc[i][7]);
  }
}

// ---------------------------------------------------------------------------
// K2: per-(b,h,l) sampled attention. 512 threads (8 waves).
// K,V row-major [512][PADK] in LDS; Q read from global (L2-resident).
// Phase D: full K slab in 64 VGPRs per wave (8 rows/lane), reused per row.
// ---------------------------------------------------------------------------
__global__ __launch_bounds__(512, 4) void attn_kernel(
    const float* __restrict__ Qt, const float* __restrict__ Kt, const float* __restrict__ Vt,
    const int* __restrict__ idxT, float* __restrict__ out) {
  const int bid = blockIdx.x;          // ((b*H + h)*L + l)
  const int l = bid % LL;
  const int h = (bid / LL) % HH;
  const int b = bid / (LL*HH);
  const int tid = threadIdx.x;
  const int wave = tid >> 6, lane = tid & 63;

  __shared__ __align__(16) float Ks[NN][PADK];
  __shared__ __align__(16) float Vs[NN][PADK];
  __shared__ float Ms[NN];
  __shared__ __align__(16) float attnRet[SK][8];
  __shared__ __align__(16) float vmean[8];
  __shared__ int topIdx[SK];
  __shared__ int sel[NN];

  const size_t slabOff = (size_t)bid * (NN*DD);

  // ---- Phase A: stage K,V rows (thread tid -> row tid), init sel, load q ----
  {
    const float4* kg = (const float4*)(Kt + slabOff) + tid*2;
    const float4* vg = (const float4*)(Vt + slabOff) + tid*2;
    float4 k0 = kg[0], k1 = kg[1];
    float4 v0 = vg[0], v1 = vg[1];
    *(float4*)&Ks[tid][0] = k0; *(float4*)&Ks[tid][4] = k1;
    *(float4*)&Vs[tid][0] = v0; *(float4*)&Vs[tid][4] = v1;
    sel[tid] = -1;
  }
  const float4* qg = (const float4*)(Qt + slabOff) + tid*2;
  float4 q0 = qg[0], q1 = qg[1];      // own row's q (issued before barrier)
  __syncthreads();

  // ---- Phase B: M[r] over 35 sampled keys (1 row per thread) ----
  {
    const int* gi = idxT + tid;
    float mx = -INFINITY, sm = 0.f;
    #pragma unroll
    for (int s = 0; s < SK; ++s) {
      int j = gi[s*NN];
      float4 k0 = *(const float4*)&Ks[j][0];
      float4 k1 = *(const float4*)&Ks[j][4];
      float dot = q0.x*k0.x + q0.y*k0.y + q0.z*k0.z + q0.w*k0.w
                + q1.x*k1.x + q1.y*k1.y + q1.z*k1.z + q1.w*k1.w;
      mx = fmaxf(mx, dot);
      sm += dot;
    }
    Ms[tid] = mx - sm * (1.0f/NN);
  }
  __syncthreads();

  // ---- Phase C (overlapped): wave0 = exact top-35; wave1 = vmean;
  //      all waves preload K into registers for phase D ----
  float4 kr[16];
  #pragma unroll
  for (int j = 0; j < 8; ++j) {
    int n = lane + 64*j;
    kr[2*j]   = *(const float4*)&Ks[n][0];
    kr[2*j+1] = *(const float4*)&Ks[n][4];
  }
  if (wave == 0) {
    float mv[8];
    #pragma unroll
    for (int j = 0; j < 8; ++j) mv[j] = Ms[lane + 64*j];
    float pv = INFINITY; int pi = -1;
    for (int t = 0; t < SK; ++t) {
      float bvv = -INFINITY; int bi = NN;
      #pragma unroll
      for (int j = 0; j < 8; ++j) {
        int r = lane + 64*j;
        float vv = mv[j];
        bool adm = (vv < pv) || (vv == pv && r > pi);
        if (adm && (vv > bvv || (vv == bvv && r < bi))) { bvv = vv; bi = r; }
      }
      #pragma unroll
      for (int off = 32; off >= 1; off >>= 1) {
        float ov = __shfl_xor(bvv, off);
        int   oi = __shfl_xor(bi, off);
        if (ov > bvv || (ov == bvv && oi < bi)) { bvv = ov; bi = oi; }
      }
      if (lane == 0) topIdx[t] = bi;
      pv = bvv; pi = bi;
    }
    if (lane < SK) sel[topIdx[lane]] = lane;
  } else if (wave == 1) {
    float4 s0 = make_float4(0,0,0,0), s1 = make_float4(0,0,0,0);
    #pragma unroll
    for (int j = 0; j < 8; ++j) {
      int n = lane + 64*j;
      float4 v0 = *(const float4*)&Vs[n][0];
      float4 v1 = *(const float4*)&Vs[n][4];
      s0.x+=v0.x; s0.y+=v0.y; s0.z+=v0.z; s0.w+=v0.w;
      s1.x+=v1.x; s1.y+=v1.y; s1.z+=v1.z; s1.w+=v1.w;
    }
    #pragma unroll
    for (int off = 32; off >= 1; off >>= 1) {
      s0.x += __shfl_xor(s0.x, off); s0.y += __shfl_xor(s0.y, off);
      s0.z += __shfl_xor(s0.z, off); s0.w += __shfl_xor(s0.w, off);
      s1.x += __shfl_xor(s1.x, off); s1.y += __shfl_xor(s1.y, off);
      s1.z += __shfl_xor(s1.z, off); s1.w += __shfl_xor(s1.w, off);
    }
    if (lane == 0) {
      const float inv = 1.0f/NN;
      *(float4*)&vmean[0] = make_float4(s0.x*inv, s0.y*inv, s0.z*inv, s0.w*inv);
      *(float4*)&vmean[4] = make_float4(s1.x*inv, s1.y*inv, s1.z*inv, s1.w*inv);
    }
  }
  __syncthreads();

  // ---- Phase D: rows t = wave, wave+8, ... (K in regs, V from LDS once/row)
  for (int t = wave; t < SK; t += 8) {
    const int row = topIdx[t];
    const float4* qr = (const float4*)(Qt + slabOff + (size_t)row*DD);
    float4 qa = qr[0], qb = qr[1];     // broadcast (all lanes same addr)
    float p[8]; float mx = -INFINITY;
    #pragma unroll
    for (int j = 0; j < 8; ++j) {
      float4 ka = kr[2*j], kb = kr[2*j+1];
      float s = qa.x*ka.x + qa.y*ka.y + qa.z*ka.z + qa.w*ka.w
              + qb.x*kb.x + qb.y*kb.y + qb.z*kb.z + qb.w*kb.w;
      s *= 0.35355339059327373f;       // 1/sqrt(8)
      p[j] = s;
      mx = fmaxf(mx, s);
    }
    #pragma unroll
    for (int off = 32; off >= 1; off >>= 1) mx = fmaxf(mx, __shfl_xor(mx, off));
    float sum = 0.f;
    #pragma unroll
    for (int j = 0; j < 8; ++j) { p[j] = __expf(p[j] - mx); sum += p[j]; }
    #pragma unroll
    for (int off = 32; off >= 1; off >>= 1) sum += __shfl_xor(sum, off);
    float4 a0 = make_float4(0,0,0,0), a1 = make_float4(0,0,0,0);
    #pragma unroll
    for (int j = 0; j < 8; ++j) {
      int n = lane + 64*j;
      float4 v0 = *(const float4*)&Vs[n][0];
      float4 v1 = *(const float4*)&Vs[n][4];
      float pj = p[j];
      a0.x = fmaf(pj, v0.x, a0.x); a0.y = fmaf(pj, v0.y, a0.y);
      a0.z = fmaf(pj, v0.z, a0.z); a0.w = fmaf(pj, v0.w, a0.w);
      a1.x = fmaf(pj, v1.x, a1.x); a1.y = fmaf(pj, v1.y, a1.y);
      a1.z = fmaf(pj, v1.z, a1.z); a1.w = fmaf(pj, v1.w, a1.w);
    }
    #pragma unroll
    for (int off = 32; off >= 1; off >>= 1) {
      a0.x += __shfl_xor(a0.x, off); a0.y += __shfl_xor(a0.y, off);
      a0.z += __shfl_xor(a0.z, off); a0.w += __shfl_xor(a0.w, off);
      a1.x += __shfl_xor(a1.x, off); a1.y += __shfl_xor(a1.y, off);
      a1.z += __shfl_xor(a1.z, off); a1.w += __shfl_xor(a1.w, off);
    }
    if (lane == 0) {
      float inv = 1.0f / sum;
      *(float4*)&attnRet[t][0] = make_float4(a0.x*inv, a0.y*inv, a0.z*inv, a0.w*inv);
      *(float4*)&attnRet[t][4] = make_float4(a1.x*inv, a1.y*inv, a1.z*inv, a1.w*inv);
    }
  }
  __syncthreads();

  // ---- Phase F: out[b][l][n][h*8+c], thread tid -> n = tid ----
  {
    int t = sel[tid];
    float4 o0, o1;
    if (t >= 0) { o0 = *(const float4*)&attnRet[t][0]; o1 = *(const float4*)&attnRet[t][4]; }
    else        { o0 = *(const float4*)&vmean[0];      o1 = *(const float4*)&vmean[4]; }
    float* ob = out + ((size_t)(b*LL + l)*NN + tid)*DMM + h*DD;
    *(float4*)&ob[0] = o0;
    *(float4*)&ob[4] = o1;
  }
}

// ---------------------------------------------------------------------------
extern "C" void kernel_launch(void* const* d_in, const int* in_sizes, int n_in,
                              void* d_out, int out_size, void* d_ws, size_t ws_size,
                              hipStream_t stream) {
  const float* q  = (const float*)d_in[0];
  const float* k  = (const float*)d_in[1];
  const float* v  = (const float*)d_in[2];
  const float* Wq = (const float*)d_in[3];
  const float* bq = (const float*)d_in[4];
  const float* Wk = (const float*)d_in[5];
  const float* bk = (const float*)d_in[6];
  const float* Wv = (const float*)d_in[7];
  const float* bv = (const float*)d_in[8];
  float* out = (float*)d_out;

  const size_t slab = (size_t)BB*HH*LL*NN*DD;
  float* qT = (float*)d_ws;
  float* kT = qT + slab;
  float* vT = kT + slab;
  int* idxT = (int*)(vT + slab);

  proj_idx_kernel<<<dim3((BB*LL*NN)/128, 4), 256, 0, stream>>>(
      q, k, v, Wq, Wk, Wv, bq, bk, bv, qT, kT, vT, idxT);
  attn_kernel<<<BB*HH*LL, 512, 0, stream>>>(qT, kT, vT, idxT, out);
}

// Round 4
// 128.372 us; speedup vs baseline: 1.0129x; 1.0129x over previous
//
#include <hip/hip_runtime.h>
#include <stdint.h>
#include <math.h>

#define BB 4
#define LL 12
#define NN 512
#define DMM 64
#define HH 8
#define DD 8
#define SK 35
#define IDX_TOTAL (NN*SK)   // 17920
#define PADK 12             // 48B row pitch: b128-aligned, conflict-free bank walk

// ---------------------------------------------------------------------------
// Threefry-2x32 (JAX-exact: 20 rounds, rotations {13,15,26,6}/{17,29,16,24})
// ---------------------------------------------------------------------------
__device__ __forceinline__ void tf2x32(uint32_t k0, uint32_t k1, uint32_t x0, uint32_t x1,
                                       uint32_t& o0, uint32_t& o1) {
  const uint32_t ks2 = k0 ^ k1 ^ 0x1BD11BDAu;
  uint32_t a = x0 + k0, b = x1 + k1;
#define TF_R(r) { a += b; b = (b << (r)) | (b >> (32 - (r))); b ^= a; }
  TF_R(13) TF_R(15) TF_R(26) TF_R(6)
  a += k1;  b += ks2 + 1u;
  TF_R(17) TF_R(29) TF_R(16) TF_R(24)
  a += ks2; b += k0 + 2u;
  TF_R(13) TF_R(15) TF_R(26) TF_R(6)
  a += k0;  b += k1 + 3u;
  TF_R(17) TF_R(29) TF_R(16) TF_R(24)
  a += k1;  b += ks2 + 4u;
  TF_R(13) TF_R(15) TF_R(26) TF_R(6)
  a += ks2; b += k0 + 5u;
#undef TF_R
  o0 = a; o1 = b;
}

// ---------------------------------------------------------------------------
// K1: fused projections (y=0,1,2) + idx generation (y=3).
// ---------------------------------------------------------------------------
__global__ __launch_bounds__(256) void proj_idx_kernel(
    const float* __restrict__ Xq, const float* __restrict__ Xk, const float* __restrict__ Xv,
    const float* __restrict__ Wq_, const float* __restrict__ Wk_, const float* __restrict__ Wv_,
    const float* __restrict__ bq_, const float* __restrict__ bk_, const float* __restrict__ bv_,
    float* __restrict__ Oq, float* __restrict__ Ok, float* __restrict__ Ov,
    int* __restrict__ idxT) {
  const int tz = blockIdx.y;
  if (tz == 3) {
    int gid = blockIdx.x * 256 + threadIdx.x;
    if (gid < IDX_TOTAL) {
      int r = gid & (NN - 1);     // idxT flat = s*512 + r
      int s = gid >> 9;
      uint32_t ka, kb;
      tf2x32(0u, 42u, 0u, 1u, ka, kb);
      uint32_t b1, b2;
      tf2x32(ka, kb, 0u, (uint32_t)(r * SK + s), b1, b2);   // counter = row-major (r,s)
      idxT[gid] = (int)((b1 ^ b2) & (uint32_t)(NN - 1));
    }
    return;
  }
  const float* X    = (tz == 0) ? Xq  : (tz == 1) ? Xk  : Xv;
  const float* W    = (tz == 0) ? Wq_ : (tz == 1) ? Wk_ : Wv_;
  const float* bias = (tz == 0) ? bq_ : (tz == 1) ? bk_ : bv_;
  float* O          = (tz == 0) ? Oq  : (tz == 1) ? Ok  : Ov;

  __shared__ __align__(16) float Ws[64][64];
  __shared__ __align__(16) float Xs[128][68];
  __shared__ float bs[64];

  const int tid = threadIdx.x;
  for (int i = tid; i < 1024; i += 256)
    ((float4*)Ws)[i] = ((const float4*)W)[i];
  if (tid < 64) bs[tid] = bias[tid];
  const size_t rowBase = (size_t)blockIdx.x * 128;
  const float* Xb = X + rowBase * 64;
  for (int i = tid; i < 2048; i += 256) {
    int r = i >> 4, c = (i & 15) << 2;
    *(float4*)&Xs[r][c] = ((const float4*)Xb)[i];
  }
  __syncthreads();

  const int hcol = tid & 7;
  const int rb   = tid >> 3;
  float4 bv0 = *(float4*)&bs[hcol*8];
  float4 bv1 = *(float4*)&bs[hcol*8+4];
  float acc[4][8];
  #pragma unroll
  for (int i = 0; i < 4; ++i) {
    acc[i][0]=bv0.x; acc[i][1]=bv0.y; acc[i][2]=bv0.z; acc[i][3]=bv0.w;
    acc[i][4]=bv1.x; acc[i][5]=bv1.y; acc[i][6]=bv1.z; acc[i][7]=bv1.w;
  }
  #pragma unroll 4
  for (int m = 0; m < 64; ++m) {
    float4 w0 = *(const float4*)&Ws[m][hcol*8];
    float4 w1 = *(const float4*)&Ws[m][hcol*8+4];
    #pragma unroll
    for (int i = 0; i < 4; ++i) {
      float x = Xs[rb + 32*i][m];
      acc[i][0] = fmaf(x, w0.x, acc[i][0]);
      acc[i][1] = fmaf(x, w0.y, acc[i][1]);
      acc[i][2] = fmaf(x, w0.z, acc[i][2]);
      acc[i][3] = fmaf(x, w0.w, acc[i][3]);
      acc[i][4] = fmaf(x, w1.x, acc[i][4]);
      acc[i][5] = fmaf(x, w1.y, acc[i][5]);
      acc[i][6] = fmaf(x, w1.z, acc[i][6]);
      acc[i][7] = fmaf(x, w1.w, acc[i][7]);
    }
  }
  #pragma unroll
  for (int i = 0; i < 4; ++i) {
    size_t R = rowBase + rb + 32*i;
    int bI = (int)(R / (LL*NN));
    int lI = (int)((R / NN) % LL);
    int nI = (int)(R % NN);
    size_t off = ((((size_t)bI*HH + hcol)*LL + lI)*NN + nI)*DD;
    *(float4*)&O[off]     = make_float4(acc[i][0],acc[i][1],acc[i][2],acc[i][3]);
    *(float4*)&O[off + 4] = make_float4(acc[i][4],acc[i][5],acc[i][6],acc[i][7]);
  }
}

// ---------------------------------------------------------------------------
// K2: per-(b,h,l) sampled attention. 512 threads (8 waves).
// K,V row-major [512][PADK] in LDS. Phase D: 2 rows per K/V sweep; acc
// reduced via per-wave LDS scratchpad (no barrier, wave-local).
// ---------------------------------------------------------------------------
__global__ __launch_bounds__(512) void attn_kernel(
    const float* __restrict__ Qt, const float* __restrict__ Kt, const float* __restrict__ Vt,
    const int* __restrict__ idxT, float* __restrict__ out) {
  const int bid = blockIdx.x;          // ((b*H + h)*L + l)
  const int l = bid % LL;
  const int h = (bid / LL) % HH;
  const int b = bid / (LL*HH);
  const int tid = threadIdx.x;
  const int wave = tid >> 6, lane = tid & 63;

  __shared__ __align__(16) float Ks[NN][PADK];
  __shared__ __align__(16) float Vs[NN][PADK];
  __shared__ __align__(16) float redbuf[8][64][8];
  __shared__ float Ms[NN];
  __shared__ __align__(16) float attnRet[SK][8];
  __shared__ __align__(16) float vmean[8];
  __shared__ int topIdx[SK];
  __shared__ int sel[NN];

  const size_t slabOff = (size_t)bid * (NN*DD);

  // ---- Phase A: stage K,V rows (thread tid -> row tid), init sel, load q ----
  {
    const float4* kg = (const float4*)(Kt + slabOff) + tid*2;
    const float4* vg = (const float4*)(Vt + slabOff) + tid*2;
    float4 k0 = kg[0], k1 = kg[1];
    float4 v0 = vg[0], v1 = vg[1];
    *(float4*)&Ks[tid][0] = k0; *(float4*)&Ks[tid][4] = k1;
    *(float4*)&Vs[tid][0] = v0; *(float4*)&Vs[tid][4] = v1;
    sel[tid] = -1;
  }
  const float4* qg = (const float4*)(Qt + slabOff) + tid*2;
  float4 q0 = qg[0], q1 = qg[1];      // own row's q (issued before barrier)
  __syncthreads();

  // ---- Phase B: M[r] over 35 sampled keys (1 row per thread) ----
  {
    const int* gi = idxT + tid;
    float mx = -INFINITY, sm = 0.f;
    #pragma unroll
    for (int s = 0; s < SK; ++s) {
      int j = gi[s*NN];
      float4 k0 = *(const float4*)&Ks[j][0];
      float4 k1 = *(const float4*)&Ks[j][4];
      float dot = q0.x*k0.x + q0.y*k0.y + q0.z*k0.z + q0.w*k0.w
                + q1.x*k1.x + q1.y*k1.y + q1.z*k1.z + q1.w*k1.w;
      mx = fmaxf(mx, dot);
      sm += dot;
    }
    Ms[tid] = mx - sm * (1.0f/NN);
  }
  __syncthreads();

  // ---- Phase C: wave0 = exact top-35 (value desc, index asc); wave1 = vmean ----
  if (wave == 0) {
    float mv[8];
    #pragma unroll
    for (int j = 0; j < 8; ++j) mv[j] = Ms[lane + 64*j];
    float pv = INFINITY; int pi = -1;
    for (int t = 0; t < SK; ++t) {
      float bvv = -INFINITY; int bi = NN;
      #pragma unroll
      for (int j = 0; j < 8; ++j) {
        int r = lane + 64*j;
        float vv = mv[j];
        bool adm = (vv < pv) || (vv == pv && r > pi);
        if (adm && (vv > bvv || (vv == bvv && r < bi))) { bvv = vv; bi = r; }
      }
      #pragma unroll
      for (int off = 32; off >= 1; off >>= 1) {
        float ov = __shfl_xor(bvv, off);
        int   oi = __shfl_xor(bi, off);
        if (ov > bvv || (ov == bvv && oi < bi)) { bvv = ov; bi = oi; }
      }
      if (lane == 0) topIdx[t] = bi;
      pv = bvv; pi = bi;
    }
    if (lane < SK) sel[topIdx[lane]] = lane;
  } else if (wave == 1) {
    float4 s0 = make_float4(0,0,0,0), s1 = make_float4(0,0,0,0);
    #pragma unroll
    for (int j = 0; j < 8; ++j) {
      int n = lane + 64*j;
      float4 v0 = *(const float4*)&Vs[n][0];
      float4 v1 = *(const float4*)&Vs[n][4];
      s0.x+=v0.x; s0.y+=v0.y; s0.z+=v0.z; s0.w+=v0.w;
      s1.x+=v1.x; s1.y+=v1.y; s1.z+=v1.z; s1.w+=v1.w;
    }
    #pragma unroll
    for (int off = 32; off >= 1; off >>= 1) {
      s0.x += __shfl_xor(s0.x, off); s0.y += __shfl_xor(s0.y, off);
      s0.z += __shfl_xor(s0.z, off); s0.w += __shfl_xor(s0.w, off);
      s1.x += __shfl_xor(s1.x, off); s1.y += __shfl_xor(s1.y, off);
      s1.z += __shfl_xor(s1.z, off); s1.w += __shfl_xor(s1.w, off);
    }
    if (lane == 0) {
      const float inv = 1.0f/NN;
      *(float4*)&vmean[0] = make_float4(s0.x*inv, s0.y*inv, s0.z*inv, s0.w*inv);
      *(float4*)&vmean[4] = make_float4(s1.x*inv, s1.y*inv, s1.z*inv, s1.w*inv);
    }
  }
  __syncthreads();

  // ---- Phase D: pair-processed rows. wave w owns t in {w, w+8, w+16, w+24, w+32<35}.
  auto do_rows = [&](int t1, int t2, bool has2) {
    const int r1 = topIdx[t1];
    const int r2 = has2 ? topIdx[t2] : r1;
    const float4* q1p = (const float4*)(Qt + slabOff + (size_t)r1*DD);
    const float4* q2p = (const float4*)(Qt + slabOff + (size_t)r2*DD);
    float4 q1a = q1p[0], q1b = q1p[1];     // broadcast loads
    float4 q2a = q2p[0], q2b = q2p[1];
    float p1[8], p2[8];
    float mx1 = -INFINITY, mx2 = -INFINITY;
    #pragma unroll
    for (int j = 0; j < 8; ++j) {
      int n = lane + 64*j;
      float4 ka = *(const float4*)&Ks[n][0];
      float4 kb = *(const float4*)&Ks[n][4];
      float s1 = q1a.x*ka.x + q1a.y*ka.y + q1a.z*ka.z + q1a.w*ka.w
               + q1b.x*kb.x + q1b.y*kb.y + q1b.z*kb.z + q1b.w*kb.w;
      float s2 = q2a.x*ka.x + q2a.y*ka.y + q2a.z*ka.z + q2a.w*ka.w
               + q2b.x*kb.x + q2b.y*kb.y + q2b.z*kb.z + q2b.w*kb.w;
      s1 *= 0.35355339059327373f;          // 1/sqrt(8)
      s2 *= 0.35355339059327373f;
      p1[j] = s1; p2[j] = s2;
      mx1 = fmaxf(mx1, s1); mx2 = fmaxf(mx2, s2);
    }
    #pragma unroll
    for (int off = 32; off >= 1; off >>= 1) {
      mx1 = fmaxf(mx1, __shfl_xor(mx1, off));
      mx2 = fmaxf(mx2, __shfl_xor(mx2, off));
    }
    float sum1 = 0.f, sum2 = 0.f;
    #pragma unroll
    for (int j = 0; j < 8; ++j) {
      p1[j] = __expf(p1[j] - mx1); sum1 += p1[j];
      p2[j] = __expf(p2[j] - mx2); sum2 += p2[j];
    }
    #pragma unroll
    for (int off = 32; off >= 1; off >>= 1) {
      sum1 += __shfl_xor(sum1, off);
      sum2 += __shfl_xor(sum2, off);
    }
    float a1[8] = {0,0,0,0,0,0,0,0}, a2[8] = {0,0,0,0,0,0,0,0};
    #pragma unroll
    for (int j = 0; j < 8; ++j) {
      int n = lane + 64*j;
      float4 va = *(const float4*)&Vs[n][0];
      float4 vb = *(const float4*)&Vs[n][4];
      float w1 = p1[j], w2 = p2[j];
      a1[0]=fmaf(w1,va.x,a1[0]); a1[1]=fmaf(w1,va.y,a1[1]);
      a1[2]=fmaf(w1,va.z,a1[2]); a1[3]=fmaf(w1,va.w,a1[3]);
      a1[4]=fmaf(w1,vb.x,a1[4]); a1[5]=fmaf(w1,vb.y,a1[5]);
      a1[6]=fmaf(w1,vb.z,a1[6]); a1[7]=fmaf(w1,vb.w,a1[7]);
      a2[0]=fmaf(w2,va.x,a2[0]); a2[1]=fmaf(w2,va.y,a2[1]);
      a2[2]=fmaf(w2,va.z,a2[2]); a2[3]=fmaf(w2,va.w,a2[3]);
      a2[4]=fmaf(w2,vb.x,a2[4]); a2[5]=fmaf(w2,vb.y,a2[5]);
      a2[6]=fmaf(w2,vb.z,a2[6]); a2[7]=fmaf(w2,vb.w,a2[7]);
    }
    const int d = lane & 7, g = lane >> 3;
    {
      *(float4*)&redbuf[wave][lane][0] = make_float4(a1[0],a1[1],a1[2],a1[3]);
      *(float4*)&redbuf[wave][lane][4] = make_float4(a1[4],a1[5],a1[6],a1[7]);
      float s = 0.f;
      #pragma unroll
      for (int k = 0; k < 8; ++k) s += redbuf[wave][g*8+k][d];
      s += __shfl_xor(s, 8); s += __shfl_xor(s, 16); s += __shfl_xor(s, 32);
      if (lane < 8) attnRet[t1][lane] = s * (1.0f / sum1);
    }
    if (has2) {
      *(float4*)&redbuf[wave][lane][0] = make_float4(a2[0],a2[1],a2[2],a2[3]);
      *(float4*)&redbuf[wave][lane][4] = make_float4(a2[4],a2[5],a2[6],a2[7]);
      float s = 0.f;
      #pragma unroll
      for (int k = 0; k < 8; ++k) s += redbuf[wave][g*8+k][d];
      s += __shfl_xor(s, 8); s += __shfl_xor(s, 16); s += __shfl_xor(s, 32);
      if (lane < 8) attnRet[t2][lane] = s * (1.0f / sum2);
    }
  };
  do_rows(wave, wave + 8, true);
  do_rows(wave + 16, wave + 24, true);
  if (wave < 3) do_rows(wave + 32, wave + 32, false);
  __syncthreads();

  // ---- Phase F: out[b][l][n][h*8+c], thread tid -> n = tid ----
  {
    int t = sel[tid];
    float4 o0, o1;
    if (t >= 0) { o0 = *(const float4*)&attnRet[t][0]; o1 = *(const float4*)&attnRet[t][4]; }
    else        { o0 = *(const float4*)&vmean[0];      o1 = *(const float4*)&vmean[4]; }
    float* ob = out + ((size_t)(b*LL + l)*NN + tid)*DMM + h*DD;
    *(float4*)&ob[0] = o0;
    *(float4*)&ob[4] = o1;
  }
}

// ---------------------------------------------------------------------------
extern "C" void kernel_launch(void* const* d_in, const int* in_sizes, int n_in,
                              void* d_out, int out_size, void* d_ws, size_t ws_size,
                              hipStream_t stream) {
  const float* q  = (const float*)d_in[0];
  const float* k  = (const float*)d_in[1];
  const float* v  = (const float*)d_in[2];
  const float* Wq = (const float*)d_in[3];
  const float* bq = (const float*)d_in[4];
  const float* Wk = (const float*)d_in[5];
  const float* bk = (const float*)d_in[6];
  const float* Wv = (const float*)d_in[7];
  const float* bv = (const float*)d_in[8];
  float* out = (float*)d_out;

  const size_t slab = (size_t)BB*HH*LL*NN*DD;
  float* qT = (float*)d_ws;
  float* kT = qT + slab;
  float* vT = kT + slab;
  int* idxT = (int*)(vT + slab);

  proj_idx_kernel<<<dim3((BB*LL*NN)/128, 4), 256, 0, stream>>>(
      q, k, v, Wq, Wk, Wv, bq, bk, bv, qT, kT, vT, idxT);
  attn_kernel<<<BB*HH*LL, 512, 0, stream>>>(qT, kT, vT, idxT, out);
}

// Round 5
// 93.767 us; speedup vs baseline: 1.3867x; 1.3690x over previous
//
#include <hip/hip_runtime.h>
#include <stdint.h>
#include <math.h>

#define BB 4
#define LL 12
#define NN 512
#define DMM 64
#define HH 8
#define DD 8
#define SK 35
#define IDX_TOTAL (NN*SK)   // 17920
#define PADK 12             // 48B row pitch: b128-aligned, 8-bank rotation

// ---------------------------------------------------------------------------
// Threefry-2x32 (JAX-exact: 20 rounds, rotations {13,15,26,6}/{17,29,16,24})
// ---------------------------------------------------------------------------
__device__ __forceinline__ void tf2x32(uint32_t k0, uint32_t k1, uint32_t x0, uint32_t x1,
                                       uint32_t& o0, uint32_t& o1) {
  const uint32_t ks2 = k0 ^ k1 ^ 0x1BD11BDAu;
  uint32_t a = x0 + k0, b = x1 + k1;
#define TF_R(r) { a += b; b = (b << (r)) | (b >> (32 - (r))); b ^= a; }
  TF_R(13) TF_R(15) TF_R(26) TF_R(6)
  a += k1;  b += ks2 + 1u;
  TF_R(17) TF_R(29) TF_R(16) TF_R(24)
  a += ks2; b += k0 + 2u;
  TF_R(13) TF_R(15) TF_R(26) TF_R(6)
  a += k0;  b += k1 + 3u;
  TF_R(17) TF_R(29) TF_R(16) TF_R(24)
  a += k1;  b += ks2 + 4u;
  TF_R(13) TF_R(15) TF_R(26) TF_R(6)
  a += ks2; b += k0 + 5u;
#undef TF_R
  o0 = a; o1 = b;
}

// ---------------------------------------------------------------------------
// K1: fused projections (y=0,1,2) + idx generation (y=3).
// ---------------------------------------------------------------------------
__global__ __launch_bounds__(256) void proj_idx_kernel(
    const float* __restrict__ Xq, const float* __restrict__ Xk, const float* __restrict__ Xv,
    const float* __restrict__ Wq_, const float* __restrict__ Wk_, const float* __restrict__ Wv_,
    const float* __restrict__ bq_, const float* __restrict__ bk_, const float* __restrict__ bv_,
    float* __restrict__ Oq, float* __restrict__ Ok, float* __restrict__ Ov,
    int* __restrict__ idxT) {
  const int tz = blockIdx.y;
  if (tz == 3) {
    int gid = blockIdx.x * 256 + threadIdx.x;
    if (gid < IDX_TOTAL) {
      int r = gid & (NN - 1);     // idxT flat = s*512 + r
      int s = gid >> 9;
      uint32_t ka, kb;
      tf2x32(0u, 42u, 0u, 1u, ka, kb);
      uint32_t b1, b2;
      tf2x32(ka, kb, 0u, (uint32_t)(r * SK + s), b1, b2);   // counter = row-major (r,s)
      idxT[gid] = (int)((b1 ^ b2) & (uint32_t)(NN - 1));
    }
    return;
  }
  const float* X    = (tz == 0) ? Xq  : (tz == 1) ? Xk  : Xv;
  const float* W    = (tz == 0) ? Wq_ : (tz == 1) ? Wk_ : Wv_;
  const float* bias = (tz == 0) ? bq_ : (tz == 1) ? bk_ : bv_;
  float* O          = (tz == 0) ? Oq  : (tz == 1) ? Ok  : Ov;

  __shared__ __align__(16) float Ws[64][64];
  __shared__ __align__(16) float Xs[128][68];
  __shared__ float bs[64];

  const int tid = threadIdx.x;
  for (int i = tid; i < 1024; i += 256)
    ((float4*)Ws)[i] = ((const float4*)W)[i];
  if (tid < 64) bs[tid] = bias[tid];
  const size_t rowBase = (size_t)blockIdx.x * 128;
  const float* Xb = X + rowBase * 64;
  for (int i = tid; i < 2048; i += 256) {
    int r = i >> 4, c = (i & 15) << 2;
    *(float4*)&Xs[r][c] = ((const float4*)Xb)[i];
  }
  __syncthreads();

  const int hcol = tid & 7;
  const int rb   = tid >> 3;
  float4 bv0 = *(float4*)&bs[hcol*8];
  float4 bv1 = *(float4*)&bs[hcol*8+4];
  float acc[4][8];
  #pragma unroll
  for (int i = 0; i < 4; ++i) {
    acc[i][0]=bv0.x; acc[i][1]=bv0.y; acc[i][2]=bv0.z; acc[i][3]=bv0.w;
    acc[i][4]=bv1.x; acc[i][5]=bv1.y; acc[i][6]=bv1.z; acc[i][7]=bv1.w;
  }
  #pragma unroll 4
  for (int m = 0; m < 64; ++m) {
    float4 w0 = *(const float4*)&Ws[m][hcol*8];
    float4 w1 = *(const float4*)&Ws[m][hcol*8+4];
    #pragma unroll
    for (int i = 0; i < 4; ++i) {
      float x = Xs[rb + 32*i][m];
      acc[i][0] = fmaf(x, w0.x, acc[i][0]);
      acc[i][1] = fmaf(x, w0.y, acc[i][1]);
      acc[i][2] = fmaf(x, w0.z, acc[i][2]);
      acc[i][3] = fmaf(x, w0.w, acc[i][3]);
      acc[i][4] = fmaf(x, w1.x, acc[i][4]);
      acc[i][5] = fmaf(x, w1.y, acc[i][5]);
      acc[i][6] = fmaf(x, w1.z, acc[i][6]);
      acc[i][7] = fmaf(x, w1.w, acc[i][7]);
    }
  }
  #pragma unroll
  for (int i = 0; i < 4; ++i) {
    size_t R = rowBase + rb + 32*i;
    int bI = (int)(R / (LL*NN));
    int lI = (int)((R / NN) % LL);
    int nI = (int)(R % NN);
    size_t off = ((((size_t)bI*HH + hcol)*LL + lI)*NN + nI)*DD;
    *(float4*)&O[off]     = make_float4(acc[i][0],acc[i][1],acc[i][2],acc[i][3]);
    *(float4*)&O[off + 4] = make_float4(acc[i][4],acc[i][5],acc[i][6],acc[i][7]);
  }
}

// ---------------------------------------------------------------------------
// K2: M + exact top-35 + vmean. 384 blocks x 256 threads. K in LDS only.
// Outputs: topW[bid][35] (row indices), vmeanW[bid][8].
// ---------------------------------------------------------------------------
__global__ __launch_bounds__(256) void m_kernel(
    const float* __restrict__ Qt, const float* __restrict__ Kt,
    const float* __restrict__ Vt, const int* __restrict__ idxT,
    int* __restrict__ topW, float* __restrict__ vmeanW) {
  const int bid = blockIdx.x;
  const int tid = threadIdx.x;
  const int wave = tid >> 6, lane = tid & 63;
  __shared__ __align__(16) float Ks[NN][PADK];
  __shared__ float Ms[NN];
  __shared__ __align__(16) float redM[64][8];
  const size_t slabOff = (size_t)bid * (NN*DD);

  // stage K rows tid and tid+256 (coalesced), load own q rows
  {
    const float4* kg = (const float4*)(Kt + slabOff);
    float4 a0 = kg[tid*2], a1 = kg[tid*2+1];
    float4 b0 = kg[(tid+256)*2], b1 = kg[(tid+256)*2+1];
    *(float4*)&Ks[tid][0] = a0;     *(float4*)&Ks[tid][4] = a1;
    *(float4*)&Ks[tid+256][0] = b0; *(float4*)&Ks[tid+256][4] = b1;
  }
  const float4* qg = (const float4*)(Qt + slabOff);
  float4 q0a = qg[tid*2], q0b = qg[tid*2+1];
  float4 q1a = qg[(tid+256)*2], q1b = qg[(tid+256)*2+1];
  __syncthreads();

  // M for row tid
  {
    const int* gi = idxT + tid;
    float mx = -INFINITY, sm = 0.f;
    #pragma unroll
    for (int s = 0; s < SK; ++s) {
      int j = gi[s*NN];
      float4 c0 = *(const float4*)&Ks[j][0];
      float4 c1 = *(const float4*)&Ks[j][4];
      float dot = q0a.x*c0.x + q0a.y*c0.y + q0a.z*c0.z + q0a.w*c0.w
                + q0b.x*c1.x + q0b.y*c1.y + q0b.z*c1.z + q0b.w*c1.w;
      mx = fmaxf(mx, dot);
      sm += dot;
    }
    Ms[tid] = mx - sm * (1.0f/NN);
  }
  // M for row tid+256
  {
    const int* gi = idxT + tid + 256;
    float mx = -INFINITY, sm = 0.f;
    #pragma unroll
    for (int s = 0; s < SK; ++s) {
      int j = gi[s*NN];
      float4 c0 = *(const float4*)&Ks[j][0];
      float4 c1 = *(const float4*)&Ks[j][4];
      float dot = q1a.x*c0.x + q1a.y*c0.y + q1a.z*c0.z + q1a.w*c0.w
                + q1b.x*c1.x + q1b.y*c1.y + q1b.z*c1.z + q1b.w*c1.w;
      mx = fmaxf(mx, dot);
      sm += dot;
    }
    Ms[tid+256] = mx - sm * (1.0f/NN);
  }
  __syncthreads();

  if (wave == 0) {
    // exact top-35 (value desc, index asc), mutation-free iterative selection
    float mv[8];
    #pragma unroll
    for (int j = 0; j < 8; ++j) mv[j] = Ms[lane + 64*j];
    int myTop = 0;
    float pv = INFINITY; int pi = -1;
    for (int t = 0; t < SK; ++t) {
      float bvv = -INFINITY; int bi = NN;
      #pragma unroll
      for (int j = 0; j < 8; ++j) {
        int r = lane + 64*j;
        float vv = mv[j];
        bool adm = (vv < pv) || (vv == pv && r > pi);
        if (adm && (vv > bvv || (vv == bvv && r < bi))) { bvv = vv; bi = r; }
      }
      #pragma unroll
      for (int off = 32; off >= 1; off >>= 1) {
        float ov = __shfl_xor(bvv, off);
        int   oi = __shfl_xor(bi, off);
        if (ov > bvv || (ov == bvv && oi < bi)) { bvv = ov; bi = oi; }
      }
      if (lane == t) myTop = bi;     // all lanes converged; lane t keeps round t
      pv = bvv; pi = bi;
    }
    if (lane < SK) topW[bid*SK + lane] = myTop;
  } else if (wave == 1) {
    // vmean from global V (coalesced)
    float a[8] = {0,0,0,0,0,0,0,0};
    #pragma unroll
    for (int j = 0; j < 8; ++j) {
      const float4* vp = (const float4*)(Vt + slabOff + (size_t)(lane + 64*j)*DD);
      float4 v0 = vp[0], v1 = vp[1];
      a[0]+=v0.x; a[1]+=v0.y; a[2]+=v0.z; a[3]+=v0.w;
      a[4]+=v1.x; a[5]+=v1.y; a[6]+=v1.z; a[7]+=v1.w;
    }
    *(float4*)&redM[lane][0] = make_float4(a[0],a[1],a[2],a[3]);
    *(float4*)&redM[lane][4] = make_float4(a[4],a[5],a[6],a[7]);
    const int d = lane & 7, g = lane >> 3;
    float s = 0.f;
    #pragma unroll
    for (int k = 0; k < 8; ++k) s += redM[g*8+k][d];
    s += __shfl_xor(s, 8); s += __shfl_xor(s, 16); s += __shfl_xor(s, 32);
    if (lane < 8) vmeanW[bid*8 + lane] = s * (1.0f/NN);
  }
}

// ---------------------------------------------------------------------------
// K3: attention + scatter-output. Block = (bhl, quarter of n-range).
// 128 threads (2 waves). K/V read from GLOBAL (L2-resident, coalesced).
// ---------------------------------------------------------------------------
__global__ __launch_bounds__(128) void d_kernel(
    const float* __restrict__ Qt, const float* __restrict__ Kt,
    const float* __restrict__ Vt, const int* __restrict__ topW,
    const float* __restrict__ vmeanW, float* __restrict__ out) {
  const int gb = blockIdx.x;
  const int bid = gb >> 2, qtr = gb & 3;
  const int l = bid % LL;
  const int h = (bid / LL) % HH;
  const int b = bid / (LL*HH);
  const int tid = threadIdx.x;
  const int wave = tid >> 6, lane = tid & 63;

  __shared__ int list[SK];
  __shared__ int cnt;
  __shared__ int flagL[128];
  __shared__ __align__(16) float attnOut[128][8];
  __shared__ __align__(16) float redD[2][64][8];
  __shared__ __align__(16) float vm[8];

  const size_t slabOff = (size_t)bid * (NN*DD);

  if (tid == 0) cnt = 0;
  if (tid < 8) vm[tid] = vmeanW[bid*8 + tid];
  flagL[tid] = 0;
  __syncthreads();
  if (tid < SK) {
    int n = topW[bid*SK + tid];
    if ((n >> 7) == qtr) { int s = atomicAdd(&cnt, 1); list[s] = n; }
  }
  __syncthreads();
  const int C = cnt;

  const float4* kp = (const float4*)(Kt + slabOff);
  const float4* vp = (const float4*)(Vt + slabOff);

  for (int it = wave*2; it < C; it += 4) {       // pair (it, it+1)
    const int n1 = list[it];
    const bool has2 = (it + 1) < C;
    const int n2 = has2 ? list[it+1] : n1;
    const float4* q1p = (const float4*)(Qt + slabOff + (size_t)n1*DD);
    const float4* q2p = (const float4*)(Qt + slabOff + (size_t)n2*DD);
    float4 q1a = q1p[0], q1b = q1p[1];
    float4 q2a = q2p[0], q2b = q2p[1];
    float p1[8], p2[8];
    float mx1 = -INFINITY, mx2 = -INFINITY;
    #pragma unroll
    for (int j = 0; j < 8; ++j) {
      int key = lane + 64*j;
      float4 ca = kp[key*2], cb = kp[key*2+1];
      float s1 = q1a.x*ca.x + q1a.y*ca.y + q1a.z*ca.z + q1a.w*ca.w
               + q1b.x*cb.x + q1b.y*cb.y + q1b.z*cb.z + q1b.w*cb.w;
      float s2 = q2a.x*ca.x + q2a.y*ca.y + q2a.z*ca.z + q2a.w*ca.w
               + q2b.x*cb.x + q2b.y*cb.y + q2b.z*cb.z + q2b.w*cb.w;
      s1 *= 0.35355339059327373f;    // 1/sqrt(8)
      s2 *= 0.35355339059327373f;
      p1[j] = s1; p2[j] = s2;
      mx1 = fmaxf(mx1, s1); mx2 = fmaxf(mx2, s2);
    }
    #pragma unroll
    for (int off = 32; off >= 1; off >>= 1) {
      mx1 = fmaxf(mx1, __shfl_xor(mx1, off));
      mx2 = fmaxf(mx2, __shfl_xor(mx2, off));
    }
    float sum1 = 0.f, sum2 = 0.f;
    #pragma unroll
    for (int j = 0; j < 8; ++j) {
      p1[j] = __expf(p1[j] - mx1); sum1 += p1[j];
      p2[j] = __expf(p2[j] - mx2); sum2 += p2[j];
    }
    #pragma unroll
    for (int off = 32; off >= 1; off >>= 1) {
      sum1 += __shfl_xor(sum1, off);
      sum2 += __shfl_xor(sum2, off);
    }
    float a1[8] = {0,0,0,0,0,0,0,0}, a2[8] = {0,0,0,0,0,0,0,0};
    #pragma unroll
    for (int j = 0; j < 8; ++j) {
      int key = lane + 64*j;
      float4 va = vp[key*2], vb = vp[key*2+1];
      float w1 = p1[j], w2 = p2[j];
      a1[0]=fmaf(w1,va.x,a1[0]); a1[1]=fmaf(w1,va.y,a1[1]);
      a1[2]=fmaf(w1,va.z,a1[2]); a1[3]=fmaf(w1,va.w,a1[3]);
      a1[4]=fmaf(w1,vb.x,a1[4]); a1[5]=fmaf(w1,vb.y,a1[5]);
      a1[6]=fmaf(w1,vb.z,a1[6]); a1[7]=fmaf(w1,vb.w,a1[7]);
      a2[0]=fmaf(w2,va.x,a2[0]); a2[1]=fmaf(w2,va.y,a2[1]);
      a2[2]=fmaf(w2,va.z,a2[2]); a2[3]=fmaf(w2,va.w,a2[3]);
      a2[4]=fmaf(w2,vb.x,a2[4]); a2[5]=fmaf(w2,vb.y,a2[5]);
      a2[6]=fmaf(w2,vb.z,a2[6]); a2[7]=fmaf(w2,vb.w,a2[7]);
    }
    const int d = lane & 7, g = lane >> 3;
    {
      *(float4*)&redD[wave][lane][0] = make_float4(a1[0],a1[1],a1[2],a1[3]);
      *(float4*)&redD[wave][lane][4] = make_float4(a1[4],a1[5],a1[6],a1[7]);
      float s = 0.f;
      #pragma unroll
      for (int k = 0; k < 8; ++k) s += redD[wave][g*8+k][d];
      s += __shfl_xor(s, 8); s += __shfl_xor(s, 16); s += __shfl_xor(s, 32);
      if (lane < 8) attnOut[n1 & 127][lane] = s * (1.0f / sum1);
      if (lane == 0) flagL[n1 & 127] = 1;
    }
    if (has2) {
      *(float4*)&redD[wave][lane][0] = make_float4(a2[0],a2[1],a2[2],a2[3]);
      *(float4*)&redD[wave][lane][4] = make_float4(a2[4],a2[5],a2[6],a2[7]);
      float s = 0.f;
      #pragma unroll
      for (int k = 0; k < 8; ++k) s += redD[wave][g*8+k][d];
      s += __shfl_xor(s, 8); s += __shfl_xor(s, 16); s += __shfl_xor(s, 32);
      if (lane < 8) attnOut[n2 & 127][lane] = s * (1.0f / sum2);
      if (lane == 0) flagL[n2 & 127] = 1;
    }
  }
  __syncthreads();

  // output 128 rows: n = qtr*128 + tid
  {
    float4 o0, o1;
    if (flagL[tid]) { o0 = *(const float4*)&attnOut[tid][0]; o1 = *(const float4*)&attnOut[tid][4]; }
    else            { o0 = *(const float4*)&vm[0];           o1 = *(const float4*)&vm[4]; }
    const int n = qtr*128 + tid;
    float* ob = out + ((size_t)(b*LL + l)*NN + n)*DMM + h*DD;
    *(float4*)&ob[0] = o0;
    *(float4*)&ob[4] = o1;
  }
}

// ---------------------------------------------------------------------------
extern "C" void kernel_launch(void* const* d_in, const int* in_sizes, int n_in,
                              void* d_out, int out_size, void* d_ws, size_t ws_size,
                              hipStream_t stream) {
  const float* q  = (const float*)d_in[0];
  const float* k  = (const float*)d_in[1];
  const float* v  = (const float*)d_in[2];
  const float* Wq = (const float*)d_in[3];
  const float* bq = (const float*)d_in[4];
  const float* Wk = (const float*)d_in[5];
  const float* bk = (const float*)d_in[6];
  const float* Wv = (const float*)d_in[7];
  const float* bv = (const float*)d_in[8];
  float* out = (float*)d_out;

  const size_t slab = (size_t)BB*HH*LL*NN*DD;    // 1,572,864 floats
  float* qT = (float*)d_ws;
  float* kT = qT + slab;
  float* vT = kT + slab;
  int*   idxT = (int*)(vT + slab);               // 17920 ints
  int*   topW = idxT + IDX_TOTAL;                // 384*35 ints
  float* vmeanW = (float*)(topW + BB*HH*LL*SK);  // 384*8 floats

  proj_idx_kernel<<<dim3((BB*LL*NN)/128, 4), 256, 0, stream>>>(
      q, k, v, Wq, Wk, Wv, bq, bk, bv, qT, kT, vT, idxT);
  m_kernel<<<BB*HH*LL, 256, 0, stream>>>(qT, kT, vT, idxT, topW, vmeanW);
  d_kernel<<<BB*HH*LL*4, 128, 0, stream>>>(qT, kT, vT, topW, vmeanW, out);
}